// Round 11
// baseline (112.668 us; speedup 1.0000x reference)
//
#include <hip/hip_runtime.h>
#include <cmath>

#define NPIX 16384
#define NATOM 1024
#define DIM 64
#define SPAR 8

// ---------------------------------------------------------------------------
// Fused pre-pass, grid-partitioned (1344 blocks) — unchanged from R10:
//   [0,256):    G 64x64 tile = D^T D + 1e-4 I, fp64 acc; Gd diag
//   [256,320):  Dt transpose
//   [320,1344): HB 128n x 128k tile (fp32, 8x8/thread)
// ---------------------------------------------------------------------------
__global__ __launch_bounds__(256) void k_pre(const float* __restrict__ X,
                                             const float* __restrict__ D,
                                             float* __restrict__ G,
                                             float* __restrict__ Dt,
                                             float* __restrict__ Gd,
                                             float* __restrict__ HB) {
  __shared__ float smem[2 * DIM * 128];  // 64 KiB
  const int b = blockIdx.x;
  if (b < 256) {
    const int i0 = (b >> 4) * 64, j0 = (b & 15) * 64;
    float(*sA)[65] = (float(*)[65])smem;
    float(*sB)[65] = (float(*)[65])(smem + DIM * 65);
    for (int t = threadIdx.x; t < DIM * 16; t += 256) {
      int d = t >> 4, c4 = (t & 15) * 4;
      *reinterpret_cast<float4*>(&sA[d][c4]) =
          *reinterpret_cast<const float4*>(&D[(size_t)d * NATOM + i0 + c4]);
      *reinterpret_cast<float4*>(&sB[d][c4]) =
          *reinterpret_cast<const float4*>(&D[(size_t)d * NATOM + j0 + c4]);
    }
    __syncthreads();
    const int ty = (threadIdx.x >> 4) * 4;
    const int tx = (threadIdx.x & 15) * 4;
    double acc[4][4];
#pragma unroll
    for (int ii = 0; ii < 4; ++ii)
#pragma unroll
      for (int jj = 0; jj < 4; ++jj) acc[ii][jj] = 0.0;
    for (int d = 0; d < DIM; ++d) {
      float a[4], bb[4];
#pragma unroll
      for (int ii = 0; ii < 4; ++ii) a[ii] = sA[d][ty + ii];
#pragma unroll
      for (int jj = 0; jj < 4; ++jj) bb[jj] = sB[d][tx + jj];
#pragma unroll
      for (int ii = 0; ii < 4; ++ii)
#pragma unroll
        for (int jj = 0; jj < 4; ++jj)
          acc[ii][jj] += (double)a[ii] * (double)bb[jj];
    }
#pragma unroll
    for (int ii = 0; ii < 4; ++ii)
#pragma unroll
      for (int jj = 0; jj < 4; ++jj) {
        const int k1 = i0 + ty + ii, k2 = j0 + tx + jj;
        float g = (float)acc[ii][jj];
        if (k1 == k2) {
          g += 1e-4f;
          Gd[k1] = g;
        }
        G[(size_t)k1 * NATOM + k2] = g;
      }
  } else if (b < 320) {
    const int base = (b - 256) * 1024 + threadIdx.x * 4;
    float4 v = *reinterpret_cast<const float4*>(&D[base]);
    const float vv[4] = {v.x, v.y, v.z, v.w};
#pragma unroll
    for (int e = 0; e < 4; ++e) {
      int idx = base + e;
      Dt[(size_t)(idx & (NATOM - 1)) * DIM + (idx >> 10)] = vv[e];
    }
  } else {
    const int bx = b - 320;
    const int n0 = (bx & 127) * 128, k0 = (bx >> 7) * 128;
    float(*sX)[128] = (float(*)[128])smem;
    float(*sD)[128] = (float(*)[128])(smem + DIM * 128);
    for (int i = threadIdx.x; i < DIM * 32; i += 256) {
      int d = i >> 5, c4 = (i & 31) * 4;
      *reinterpret_cast<float4*>(&sX[d][c4]) =
          *reinterpret_cast<const float4*>(&X[(size_t)d * NPIX + n0 + c4]);
      *reinterpret_cast<float4*>(&sD[d][c4]) =
          *reinterpret_cast<const float4*>(&D[(size_t)d * NATOM + k0 + c4]);
    }
    __syncthreads();
    const int nl = (threadIdx.x & 15) * 8;
    const int kl = (threadIdx.x >> 4) * 8;
    float acc[8][8];
#pragma unroll
    for (int i = 0; i < 8; ++i)
#pragma unroll
      for (int j = 0; j < 8; ++j) acc[i][j] = 0.f;
#pragma unroll 4
    for (int d = 0; d < DIM; ++d) {
      float xv[8], dv[8];
      *reinterpret_cast<float4*>(&xv[0]) = *reinterpret_cast<float4*>(&sX[d][nl]);
      *reinterpret_cast<float4*>(&xv[4]) = *reinterpret_cast<float4*>(&sX[d][nl + 4]);
      *reinterpret_cast<float4*>(&dv[0]) = *reinterpret_cast<float4*>(&sD[d][kl]);
      *reinterpret_cast<float4*>(&dv[4]) = *reinterpret_cast<float4*>(&sD[d][kl + 4]);
#pragma unroll
      for (int i = 0; i < 8; ++i)
#pragma unroll
        for (int j = 0; j < 8; ++j) acc[i][j] = fmaf(xv[i], dv[j], acc[i][j]);
    }
#pragma unroll
    for (int i = 0; i < 8; ++i)
#pragma unroll
      for (int j = 0; j < 2; ++j)
        *reinterpret_cast<float4*>(
            &HB[(size_t)(n0 + nl + i) * NATOM + k0 + kl + j * 4]) =
            *reinterpret_cast<float4*>(&acc[i][j * 4]);
  }
}

// ---------------------------------------------------------------------------
// DPP wave64 max-reduce (VALU latency, no LDS). HW-verified (rounds 6-10).
// ---------------------------------------------------------------------------
template <int CTRL>
__device__ __forceinline__ float dpp_fmax(float x) {
  int s = __builtin_amdgcn_update_dpp(__float_as_int(x), __float_as_int(x),
                                      CTRL, 0xf, 0xf, false);
  return fmaxf(x, __int_as_float(s));
}
__device__ __forceinline__ float wave_max_bcast(float x) {
  x = dpp_fmax<0x111>(x);  // row_shr:1
  x = dpp_fmax<0x112>(x);  // row_shr:2
  x = dpp_fmax<0x114>(x);  // row_shr:4
  x = dpp_fmax<0x118>(x);  // row_shr:8
  x = dpp_fmax<0x142>(x);  // row_bcast:15
  x = dpp_fmax<0x143>(x);  // row_bcast:31
  return __int_as_float(__builtin_amdgcn_readlane(__float_as_int(x), 63));
}

// ---------------------------------------------------------------------------
// Batched OMP, TWO WAVES PER PIXEL (128-thread block). Wave w owns atoms
// [w*512, w*512+512); lane owns k = w*512 + lane*8 + j, j=0..7 (global index
// ascending in (wave, lane, j) -> first-occurrence semantics preserved).
// Per-wave state halves vs R10 (rows[7][8]) -> 3 waves/SIMD via
// __launch_bounds__(128,3). Cross-wave argmax: each wave publishes its exact
// local {M_w, cand_w} to a parity-double-buffered LDS slot; ONE barrier per
// step; winner = max M (exact max is associative -> M bit-identical to the
// 1024-wide tree), tie -> min cand (= global first occurrence). Chol/solves
// duplicated in both waves (identical fp ops). NaN-poison by the owning
// wave. All numerics bit-identical to the passing R10 kernel.
// ---------------------------------------------------------------------------
__global__ __launch_bounds__(128, 3) void k_omp2(const float* __restrict__ HB,
                                                 const float* __restrict__ Dt,
                                                 const float* __restrict__ G,
                                                 const float* __restrict__ Gd,
                                                 float* __restrict__ out) {
  const int lane = threadIdx.x & 63;
  const int wave = threadIdx.x >> 6;
  const int kbase = wave * 512 + lane * 8;
  const int n = __builtin_amdgcn_readfirstlane(blockIdx.x);

  __shared__ float sM[2][2];
  __shared__ int sC[2][2];

  float hb[8];
#pragma unroll
  for (int q = 0; q < 2; ++q) {
    float4 v = *reinterpret_cast<const float4*>(
        &HB[(size_t)n * NATOM + kbase + q * 4]);
    hb[q * 4 + 0] = v.x; hb[q * 4 + 1] = v.y;
    hb[q * 4 + 2] = v.z; hb[q * 4 + 3] = v.w;
  }
#pragma unroll
  for (int j = 0; j < 8; ++j) asm volatile("" : "+v"(hb[j]));

  int selI[SPAR];            // wave-uniform -> SGPRs
  float rows[SPAR - 1][8];   // rows[i][j] = G[selI[i]][kbase+j], pinned
  float Lm[SPAR][SPAR], invL[SPAR], ysel[SPAR], coefF[SPAR];

#pragma unroll 8
  for (int s = 0; s < SPAR; ++s) {
    // ---- h = hb - sum_i coef_i * rows_i (ascending i; same chains as R10) --
    float h[8];
#pragma unroll
    for (int j = 0; j < 8; ++j) {
      float hv = hb[j];
#pragma unroll
      for (int i = 0; i < SPAR - 1; ++i)
        if (i < s) hv = fmaf(-coefF[i], rows[i][j], hv);
      h[j] = hv;
    }
    // ---- local wave max of |h| (abs folds into v_max modifiers) ----
    float ml = fmaxf(fmaxf(fmaxf(fabsf(h[0]), fabsf(h[1])), fabsf(h[2])), fabsf(h[3]));
    float mh = fmaxf(fmaxf(fmaxf(fabsf(h[4]), fabsf(h[5])), fabsf(h[6])), fabsf(h[7]));
    const float Mw = wave_max_bcast(fmaxf(ml, mh));
    // ---- local first match (descending j: last write = min j) ----
    unsigned cand = NATOM;
#pragma unroll
    for (int j = 7; j >= 0; --j)
      cand = (fabsf(h[j]) == Mw) ? (unsigned)(kbase + j) : cand;
    unsigned long long bal = __ballot(cand != (unsigned)NATOM);
    const int fl = __ffsll(bal) - 1;  // >=0: local max always has a match
    const int cw = __builtin_amdgcn_readlane((int)cand, fl);
    // ---- cross-wave combine (one barrier; parity double-buffer) ----
    if (lane == 0) {
      sM[s & 1][wave] = Mw;
      sC[s & 1][wave] = cw;
    }
    __syncthreads();
    const float M0 = sM[s & 1][0], M1 = sM[s & 1][1];
    const int c0 = sC[s & 1][0], c1 = sC[s & 1][1];
    int bkv;
    if (M0 > M1) bkv = c0;
    else if (M1 > M0) bkv = c1;
    else bkv = c0 < c1 ? c0 : c1;
    const int bk = __builtin_amdgcn_readfirstlane(bkv);
    selI[s] = bk;

    // hbs: wave-uniform load from memory (never poisoned)
    const float hbs = HB[(size_t)n * NATOM + bk];

    // poison the selected slot in its owning wave/lane (NaN semantics)
    if ((bk >> 9) == wave && lane == ((bk >> 3) & 63)) {
#pragma unroll
      for (int j = 0; j < 8; ++j)
        if (j == (bk & 7)) hb[j] = __builtin_nanf("");
    }

    // issue new-row fetch (dwordx4 x2); completes during chol/solve below
    if (s < SPAR - 1) {
#pragma unroll
      for (int q = 0; q < 2; ++q) {
        float4 rv = *reinterpret_cast<const float4*>(
            &G[(size_t)bk * NATOM + kbase + q * 4]);
        rows[s][q * 4 + 0] = rv.x; rows[s][q * 4 + 1] = rv.y;
        rows[s][q * 4 + 2] = rv.z; rows[s][q * 4 + 3] = rv.w;
      }
    }

    // ---- Cholesky update (duplicated in both waves; identical fp ops) ----
    const float diag = Gd[bk];  // wave-uniform scalar load
    float w[SPAR];
    float sq = 0.f;
#pragma unroll
    for (int i = 0; i < SPAR; ++i)
      if (i < s) {
        float a = G[(size_t)selI[i] * NATOM + bk];  // uniform scalar load
#pragma unroll
        for (int t = 0; t < SPAR; ++t)
          if (t < i) a = fmaf(-Lm[i][t], w[t], a);
        w[i] = a * invL[i];
        sq += w[i] * w[i];
        Lm[s][i] = w[i];
      }
    float cc = diag - sq;
    if (cc < 1e-6f) cc = 1e-6f;  // jnp.clip(..., CHOL_EPS)
    invL[s] = 1.0f / sqrtf(cc);

    // ---- y_s (incremental forward solve) ----
    {
      float a = hbs;
#pragma unroll
      for (int t = 0; t < SPAR; ++t)
        if (t < s) a = fmaf(-Lm[s][t], ysel[t], a);
      ysel[s] = a * invL[s];
    }
    // ---- coef: backward solve L^T x = y ----
#pragma unroll
    for (int i = SPAR - 1; i >= 0; --i)
      if (i <= s) {
        float a = ysel[i];
#pragma unroll
        for (int t = 0; t < SPAR; ++t)
          if (t > i && t <= s) a = fmaf(-Lm[t][i], coefF[t], a);
        coefF[i] = a * invL[i];
      }

    // pin the fetched row: residency + post-solve waitcnt placement
    if (s < SPAR - 1) {
#pragma unroll
      for (int j = 0; j < 8; ++j) asm volatile("" : "+v"(rows[s][j]));
    }
  }

  // ---- outputs: wave 0 -> recon [n][64]; wave 1 -> I and coeffs ----
  if (wave == 0) {
    double r = 0.0;
#pragma unroll
    for (int i = 0; i < SPAR; ++i)
      r += (double)coefF[i] * (double)Dt[(size_t)selI[i] * DIM + lane];
    out[(size_t)n * DIM + lane] = (float)r;
  } else {
    float fi = 0.f, fc = 0.f;
#pragma unroll
    for (int i = 0; i < SPAR; ++i)
      if (lane == i) { fi = (float)selI[i]; fc = coefF[i]; }
    if (lane < SPAR) {
      out[(size_t)NPIX * DIM + (size_t)n * SPAR + lane] = fi;
      out[(size_t)NPIX * DIM + (size_t)NPIX * SPAR + (size_t)n * SPAR + lane] = fc;
    }
  }
}

// ---------------------------------------------------------------------------
// Fallback single-wave OMP (tiny-workspace path; R10 kernel, HB computed
// in-kernel in fp64). Unchanged.
// ---------------------------------------------------------------------------
__global__ __launch_bounds__(64) void k_omp_fb(const float* __restrict__ X,
                                               const float* __restrict__ D,
                                               const float* __restrict__ G,
                                               const float* __restrict__ Gd,
                                               float* __restrict__ out) {
  const int lane = threadIdx.x & 63;
  const int lane16 = lane * 16;
  const int n = __builtin_amdgcn_readfirstlane(blockIdx.x);

  float hb[16];
  {
    double a[16];
#pragma unroll
    for (int j = 0; j < 16; ++j) a[j] = 0.0;
    for (int d = 0; d < DIM; ++d) {
      float xd = X[(size_t)d * NPIX + n];
#pragma unroll
      for (int j = 0; j < 16; ++j)
        a[j] += (double)xd * (double)D[(size_t)d * NATOM + lane16 + j];
    }
#pragma unroll
    for (int j = 0; j < 16; ++j) hb[j] = (float)a[j];
  }
#pragma unroll
  for (int j = 0; j < 16; ++j) asm volatile("" : "+v"(hb[j]));

  int selI[SPAR];
  float rows[SPAR - 1][16];
  float Lm[SPAR][SPAR], invL[SPAR], ysel[SPAR], coefF[SPAR];

#pragma unroll 8
  for (int s = 0; s < SPAR; ++s) {
    float h[16];
#pragma unroll
    for (int j = 0; j < 16; ++j) {
      float hv = hb[j];
#pragma unroll
      for (int i = 0; i < SPAR - 1; ++i)
        if (i < s) hv = fmaf(-coefF[i], rows[i][j], hv);
      h[j] = hv;
    }
    float m0 = fmaxf(fmaxf(fmaxf(fabsf(h[0]), fabsf(h[1])), fabsf(h[2])), fabsf(h[3]));
    float m1 = fmaxf(fmaxf(fmaxf(fabsf(h[4]), fabsf(h[5])), fabsf(h[6])), fabsf(h[7]));
    float m2 = fmaxf(fmaxf(fmaxf(fabsf(h[8]), fabsf(h[9])), fabsf(h[10])), fabsf(h[11]));
    float m3 = fmaxf(fmaxf(fmaxf(fabsf(h[12]), fabsf(h[13])), fabsf(h[14])), fabsf(h[15]));
    const float M = wave_max_bcast(fmaxf(fmaxf(m0, m1), fmaxf(m2, m3)));
    unsigned cand = NATOM;
#pragma unroll
    for (int j = 15; j >= 0; --j)
      cand = (fabsf(h[j]) == M) ? (unsigned)(lane16 + j) : cand;
    unsigned long long bal = __ballot(cand != (unsigned)NATOM);
    const int fl = __ffsll(bal) - 1;
    const int bk = __builtin_amdgcn_readlane((int)cand, fl);
    selI[s] = bk;
    const int bl = bk >> 4, bj = bk & 15;

    float v = 0.f;
#pragma unroll
    for (int j = 0; j < 16; ++j)
      if (j == bj) v = hb[j];
    const float hbs =
        __int_as_float(__builtin_amdgcn_readlane(__float_as_int(v), bl));

#pragma unroll
    for (int j = 0; j < 16; ++j)
      if (j == bj && lane == bl) hb[j] = __builtin_nanf("");

    if (s < SPAR - 1) {
#pragma unroll
      for (int q = 0; q < 4; ++q) {
        float4 rv = *reinterpret_cast<const float4*>(
            &G[(size_t)bk * NATOM + lane16 + q * 4]);
        rows[s][q * 4 + 0] = rv.x; rows[s][q * 4 + 1] = rv.y;
        rows[s][q * 4 + 2] = rv.z; rows[s][q * 4 + 3] = rv.w;
      }
    }

    const float diag = Gd[bk];
    float w[SPAR];
    float sq = 0.f;
#pragma unroll
    for (int i = 0; i < SPAR; ++i)
      if (i < s) {
        float a = G[(size_t)selI[i] * NATOM + bk];
#pragma unroll
        for (int t = 0; t < SPAR; ++t)
          if (t < i) a = fmaf(-Lm[i][t], w[t], a);
        w[i] = a * invL[i];
        sq += w[i] * w[i];
        Lm[s][i] = w[i];
      }
    float cc = diag - sq;
    if (cc < 1e-6f) cc = 1e-6f;
    invL[s] = 1.0f / sqrtf(cc);
    {
      float a = hbs;
#pragma unroll
      for (int t = 0; t < SPAR; ++t)
        if (t < s) a = fmaf(-Lm[s][t], ysel[t], a);
      ysel[s] = a * invL[s];
    }
#pragma unroll
    for (int i = SPAR - 1; i >= 0; --i)
      if (i <= s) {
        float a = ysel[i];
#pragma unroll
        for (int t = 0; t < SPAR; ++t)
          if (t > i && t <= s) a = fmaf(-Lm[t][i], coefF[t], a);
        coefF[i] = a * invL[i];
      }
    if (s < SPAR - 1) {
#pragma unroll
      for (int j = 0; j < 16; ++j) asm volatile("" : "+v"(rows[s][j]));
    }
  }

  double r = 0.0;
#pragma unroll
  for (int i = 0; i < SPAR; ++i)
    r += (double)coefF[i] * (double)D[(size_t)lane * NATOM + selI[i]];
  out[(size_t)n * DIM + lane] = (float)r;

  float fi = 0.f, fc = 0.f;
#pragma unroll
  for (int i = 0; i < SPAR; ++i)
    if (lane == i) { fi = (float)selI[i]; fc = coefF[i]; }
  if (lane < SPAR) {
    out[(size_t)NPIX * DIM + (size_t)n * SPAR + lane] = fi;
    out[(size_t)NPIX * DIM + (size_t)NPIX * SPAR + (size_t)n * SPAR + lane] = fc;
  }
}

__global__ __launch_bounds__(256) void k_gram(const float* __restrict__ D,
                                              float* __restrict__ G,
                                              float* __restrict__ Gd) {
  int k1 = blockIdx.x;
  __shared__ float d1[DIM];
  if (threadIdx.x < DIM) d1[threadIdx.x] = D[(size_t)threadIdx.x * NATOM + k1];
  __syncthreads();
  for (int k2 = threadIdx.x; k2 < NATOM; k2 += 256) {
    double acc = 0.0;
#pragma unroll
    for (int d = 0; d < DIM; ++d)
      acc += (double)d1[d] * (double)D[(size_t)d * NATOM + k2];
    float g = (float)acc;
    if (k2 == k1) {
      g += 1e-4f;
      Gd[k1] = g;
    }
    G[(size_t)k1 * NATOM + k2] = g;
  }
}

extern "C" void kernel_launch(void* const* d_in, const int* in_sizes, int n_in,
                              void* d_out, int out_size, void* d_ws,
                              size_t ws_size, hipStream_t stream) {
  const float* X = (const float*)d_in[0];  // [64, 16384]
  const float* D = (const float*)d_in[1];  // [64, 1024]
  float* out = (float*)d_out;              // [recon | I | coeffs] as fp32
  float* G = (float*)d_ws;                 // 4 MB
  float* Dt = G + (size_t)NATOM * NATOM;   // 256 KB
  float* Gd = Dt + (size_t)NATOM * DIM;    // 4 KB
  float* HB = Gd + NATOM;                  // 64 MB
  const size_t needFull =
      ((size_t)NATOM * NATOM + (size_t)NATOM * DIM + NATOM +
       (size_t)NPIX * NATOM) * sizeof(float);

  if (ws_size >= needFull) {
    k_pre<<<dim3(1344), dim3(256), 0, stream>>>(X, D, G, Dt, Gd, HB);
    k_omp2<<<dim3(NPIX), dim3(128), 0, stream>>>(HB, Dt, G, Gd, out);
  } else {
    k_gram<<<dim3(NATOM), dim3(256), 0, stream>>>(D, G, Gd);
    k_omp_fb<<<dim3(NPIX), dim3(64), 0, stream>>>(X, D, G, Gd, out);
  }
}

// Round 12
// 110.647 us; speedup vs baseline: 1.0183x; 1.0183x over previous
//
#include <hip/hip_runtime.h>
#include <cmath>

#define NPIX 16384
#define NATOM 1024
#define DIM 64
#define SPAR 8

// ---------------------------------------------------------------------------
// Fused pre-pass, grid-partitioned (1344 blocks) — unchanged (R9-verified):
//   [0,256):    G 64x64 tile = D^T D + 1e-4 I, fp64 acc; Gd diag
//   [256,320):  Dt transpose
//   [320,1344): HB 128n x 128k tile (fp32, 8x8/thread)
// ---------------------------------------------------------------------------
__global__ __launch_bounds__(256) void k_pre(const float* __restrict__ X,
                                             const float* __restrict__ D,
                                             float* __restrict__ G,
                                             float* __restrict__ Dt,
                                             float* __restrict__ Gd,
                                             float* __restrict__ HB) {
  __shared__ float smem[2 * DIM * 128];  // 64 KiB
  const int b = blockIdx.x;
  if (b < 256) {
    const int i0 = (b >> 4) * 64, j0 = (b & 15) * 64;
    float(*sA)[65] = (float(*)[65])smem;
    float(*sB)[65] = (float(*)[65])(smem + DIM * 65);
    for (int t = threadIdx.x; t < DIM * 16; t += 256) {
      int d = t >> 4, c4 = (t & 15) * 4;
      *reinterpret_cast<float4*>(&sA[d][c4]) =
          *reinterpret_cast<const float4*>(&D[(size_t)d * NATOM + i0 + c4]);
      *reinterpret_cast<float4*>(&sB[d][c4]) =
          *reinterpret_cast<const float4*>(&D[(size_t)d * NATOM + j0 + c4]);
    }
    __syncthreads();
    const int ty = (threadIdx.x >> 4) * 4;
    const int tx = (threadIdx.x & 15) * 4;
    double acc[4][4];
#pragma unroll
    for (int ii = 0; ii < 4; ++ii)
#pragma unroll
      for (int jj = 0; jj < 4; ++jj) acc[ii][jj] = 0.0;
    for (int d = 0; d < DIM; ++d) {
      float a[4], bb[4];
#pragma unroll
      for (int ii = 0; ii < 4; ++ii) a[ii] = sA[d][ty + ii];
#pragma unroll
      for (int jj = 0; jj < 4; ++jj) bb[jj] = sB[d][tx + jj];
#pragma unroll
      for (int ii = 0; ii < 4; ++ii)
#pragma unroll
        for (int jj = 0; jj < 4; ++jj)
          acc[ii][jj] += (double)a[ii] * (double)bb[jj];
    }
#pragma unroll
    for (int ii = 0; ii < 4; ++ii)
#pragma unroll
      for (int jj = 0; jj < 4; ++jj) {
        const int k1 = i0 + ty + ii, k2 = j0 + tx + jj;
        float g = (float)acc[ii][jj];
        if (k1 == k2) {
          g += 1e-4f;
          Gd[k1] = g;
        }
        G[(size_t)k1 * NATOM + k2] = g;
      }
  } else if (b < 320) {
    const int base = (b - 256) * 1024 + threadIdx.x * 4;
    float4 v = *reinterpret_cast<const float4*>(&D[base]);
    const float vv[4] = {v.x, v.y, v.z, v.w};
#pragma unroll
    for (int e = 0; e < 4; ++e) {
      int idx = base + e;
      Dt[(size_t)(idx & (NATOM - 1)) * DIM + (idx >> 10)] = vv[e];
    }
  } else {
    const int bx = b - 320;
    const int n0 = (bx & 127) * 128, k0 = (bx >> 7) * 128;
    float(*sX)[128] = (float(*)[128])smem;
    float(*sD)[128] = (float(*)[128])(smem + DIM * 128);
    for (int i = threadIdx.x; i < DIM * 32; i += 256) {
      int d = i >> 5, c4 = (i & 31) * 4;
      *reinterpret_cast<float4*>(&sX[d][c4]) =
          *reinterpret_cast<const float4*>(&X[(size_t)d * NPIX + n0 + c4]);
      *reinterpret_cast<float4*>(&sD[d][c4]) =
          *reinterpret_cast<const float4*>(&D[(size_t)d * NATOM + k0 + c4]);
    }
    __syncthreads();
    const int nl = (threadIdx.x & 15) * 8;
    const int kl = (threadIdx.x >> 4) * 8;
    float acc[8][8];
#pragma unroll
    for (int i = 0; i < 8; ++i)
#pragma unroll
      for (int j = 0; j < 8; ++j) acc[i][j] = 0.f;
#pragma unroll 4
    for (int d = 0; d < DIM; ++d) {
      float xv[8], dv[8];
      *reinterpret_cast<float4*>(&xv[0]) = *reinterpret_cast<float4*>(&sX[d][nl]);
      *reinterpret_cast<float4*>(&xv[4]) = *reinterpret_cast<float4*>(&sX[d][nl + 4]);
      *reinterpret_cast<float4*>(&dv[0]) = *reinterpret_cast<float4*>(&sD[d][kl]);
      *reinterpret_cast<float4*>(&dv[4]) = *reinterpret_cast<float4*>(&sD[d][kl + 4]);
#pragma unroll
      for (int i = 0; i < 8; ++i)
#pragma unroll
        for (int j = 0; j < 8; ++j) acc[i][j] = fmaf(xv[i], dv[j], acc[i][j]);
    }
#pragma unroll
    for (int i = 0; i < 8; ++i)
#pragma unroll
      for (int j = 0; j < 2; ++j)
        *reinterpret_cast<float4*>(
            &HB[(size_t)(n0 + nl + i) * NATOM + k0 + kl + j * 4]) =
            *reinterpret_cast<float4*>(&acc[i][j * 4]);
  }
}

// ---------------------------------------------------------------------------
// DPP wave64 max-reduce (VALU latency, no LDS). HW-verified (rounds 6-11).
// ---------------------------------------------------------------------------
template <int CTRL>
__device__ __forceinline__ float dpp_fmax(float x) {
  int s = __builtin_amdgcn_update_dpp(__float_as_int(x), __float_as_int(x),
                                      CTRL, 0xf, 0xf, false);
  return fmaxf(x, __int_as_float(s));
}
__device__ __forceinline__ float wave_max_bcast(float x) {
  x = dpp_fmax<0x111>(x);  // row_shr:1
  x = dpp_fmax<0x112>(x);  // row_shr:2
  x = dpp_fmax<0x114>(x);  // row_shr:4
  x = dpp_fmax<0x118>(x);  // row_shr:8
  x = dpp_fmax<0x142>(x);  // row_bcast:15
  x = dpp_fmax<0x143>(x);  // row_bcast:31
  return __int_as_float(__builtin_amdgcn_readlane(__float_as_int(x), 63));
}

// ---------------------------------------------------------------------------
// Batched OMP, TWO WAVES PER PIXEL (128-thread block), DEDUPED SOLVES.
// Wave w owns atoms [w*512, w*512+512); lane owns k = w*512+lane*8+j.
// Both waves: scores on their half + local DPP argmax (ops identical R11).
// Barrier A: combine {M,cand} -> bk (max-M, tie min-cand == np.argmax).
// ONLY WAVE 1 runs the Cholesky update + forward/backward solves, then
// publishes coefF[0..s] via LDS; barrier B; wave 0 copies the bit-exact
// values. Wave 0's next-row fetch is issued before barrier B so its latency
// hides under wave 1's serial solve chain. All fp ops bit-identical to the
// passing R11 kernel (solves computed once instead of twice).
// ---------------------------------------------------------------------------
__global__ __launch_bounds__(128, 3) void k_omp2(const float* __restrict__ HB,
                                                 const float* __restrict__ Dt,
                                                 const float* __restrict__ G,
                                                 const float* __restrict__ Gd,
                                                 float* __restrict__ out) {
  const int lane = threadIdx.x & 63;
  const int wave = threadIdx.x >> 6;
  const int kbase = wave * 512 + lane * 8;
  const int n = __builtin_amdgcn_readfirstlane(blockIdx.x);

  __shared__ float sM[2][2];
  __shared__ int sC[2][2];
  __shared__ float sCoef[SPAR];

  float hb[8];
#pragma unroll
  for (int q = 0; q < 2; ++q) {
    float4 v = *reinterpret_cast<const float4*>(
        &HB[(size_t)n * NATOM + kbase + q * 4]);
    hb[q * 4 + 0] = v.x; hb[q * 4 + 1] = v.y;
    hb[q * 4 + 2] = v.z; hb[q * 4 + 3] = v.w;
  }
#pragma unroll
  for (int j = 0; j < 8; ++j) asm volatile("" : "+v"(hb[j]));

  int selI[SPAR];            // wave-uniform -> SGPRs
  float rows[SPAR - 1][8];   // rows[i][j] = G[selI[i]][kbase+j], pinned
  float Lm[SPAR][SPAR], invL[SPAR], ysel[SPAR], coefF[SPAR];

#pragma unroll 8
  for (int s = 0; s < SPAR; ++s) {
    // ---- h = hb - sum_i coef_i * rows_i (ascending i; same chains) ----
    float h[8];
#pragma unroll
    for (int j = 0; j < 8; ++j) {
      float hv = hb[j];
#pragma unroll
      for (int i = 0; i < SPAR - 1; ++i)
        if (i < s) hv = fmaf(-coefF[i], rows[i][j], hv);
      h[j] = hv;
    }
    // ---- local wave max of |h| ----
    float ml = fmaxf(fmaxf(fmaxf(fabsf(h[0]), fabsf(h[1])), fabsf(h[2])), fabsf(h[3]));
    float mh = fmaxf(fmaxf(fmaxf(fabsf(h[4]), fabsf(h[5])), fabsf(h[6])), fabsf(h[7]));
    const float Mw = wave_max_bcast(fmaxf(ml, mh));
    // ---- local first match (descending j: last write = min j) ----
    unsigned cand = NATOM;
#pragma unroll
    for (int j = 7; j >= 0; --j)
      cand = (fabsf(h[j]) == Mw) ? (unsigned)(kbase + j) : cand;
    unsigned long long bal = __ballot(cand != (unsigned)NATOM);
    const int fl = __ffsll(bal) - 1;
    const int cw = __builtin_amdgcn_readlane((int)cand, fl);
    if (lane == 0) {
      sM[s & 1][wave] = Mw;
      sC[s & 1][wave] = cw;
    }
    __syncthreads();  // A
    const float M0 = sM[s & 1][0], M1 = sM[s & 1][1];
    const int c0 = sC[s & 1][0], c1 = sC[s & 1][1];
    int bkv;
    if (M0 > M1) bkv = c0;
    else if (M1 > M0) bkv = c1;
    else bkv = c0 < c1 ? c0 : c1;
    const int bk = __builtin_amdgcn_readfirstlane(bkv);
    selI[s] = bk;

    // poison the selected slot in its owning wave/lane (NaN semantics)
    if ((bk >> 9) == wave && lane == ((bk >> 3) & 63)) {
#pragma unroll
      for (int j = 0; j < 8; ++j)
        if (j == (bk & 7)) hb[j] = __builtin_nanf("");
    }

    // issue new-row fetch (dwordx4 x2) BEFORE barrier B: latency hides
    // under wave 1's serial chol/solve
    if (s < SPAR - 1) {
#pragma unroll
      for (int q = 0; q < 2; ++q) {
        float4 rv = *reinterpret_cast<const float4*>(
            &G[(size_t)bk * NATOM + kbase + q * 4]);
        rows[s][q * 4 + 0] = rv.x; rows[s][q * 4 + 1] = rv.y;
        rows[s][q * 4 + 2] = rv.z; rows[s][q * 4 + 3] = rv.w;
      }
    }

    if (wave == 1) {
      // ---- Cholesky update (single wave; identical fp ops to R11) ----
      const float hbs = HB[(size_t)n * NATOM + bk];  // uniform scalar load
      const float diag = Gd[bk];                     // uniform scalar load
      float w[SPAR];
      float sq = 0.f;
#pragma unroll
      for (int i = 0; i < SPAR; ++i)
        if (i < s) {
          float a = G[(size_t)selI[i] * NATOM + bk];  // uniform scalar load
#pragma unroll
          for (int t = 0; t < SPAR; ++t)
            if (t < i) a = fmaf(-Lm[i][t], w[t], a);
          w[i] = a * invL[i];
          sq += w[i] * w[i];
          Lm[s][i] = w[i];
        }
      float cc = diag - sq;
      if (cc < 1e-6f) cc = 1e-6f;  // jnp.clip(..., CHOL_EPS)
      invL[s] = 1.0f / sqrtf(cc);

      // ---- y_s (incremental forward solve) ----
      {
        float a = hbs;
#pragma unroll
        for (int t = 0; t < SPAR; ++t)
          if (t < s) a = fmaf(-Lm[s][t], ysel[t], a);
        ysel[s] = a * invL[s];
      }
      // ---- coef: backward solve L^T x = y ----
#pragma unroll
      for (int i = SPAR - 1; i >= 0; --i)
        if (i <= s) {
          float a = ysel[i];
#pragma unroll
          for (int t = 0; t < SPAR; ++t)
            if (t > i && t <= s) a = fmaf(-Lm[t][i], coefF[t], a);
          coefF[i] = a * invL[i];
        }
      // publish bit-exact coefs
      if (lane == 0) {
#pragma unroll
        for (int i = 0; i < SPAR; ++i)
          if (i <= s) sCoef[i] = coefF[i];
      }
    }
    __syncthreads();  // B
    if (wave == 0) {
#pragma unroll
      for (int i = 0; i < SPAR; ++i)
        if (i <= s) coefF[i] = sCoef[i];
    }

    // pin the fetched row: residency + post-solve waitcnt placement
    if (s < SPAR - 1) {
#pragma unroll
      for (int j = 0; j < 8; ++j) asm volatile("" : "+v"(rows[s][j]));
    }
  }

  // ---- outputs: wave 0 -> recon [n][64]; wave 1 -> I and coeffs ----
  if (wave == 0) {
    double r = 0.0;
#pragma unroll
    for (int i = 0; i < SPAR; ++i)
      r += (double)coefF[i] * (double)Dt[(size_t)selI[i] * DIM + lane];
    out[(size_t)n * DIM + lane] = (float)r;
  } else {
    float fi = 0.f, fc = 0.f;
#pragma unroll
    for (int i = 0; i < SPAR; ++i)
      if (lane == i) { fi = (float)selI[i]; fc = coefF[i]; }
    if (lane < SPAR) {
      out[(size_t)NPIX * DIM + (size_t)n * SPAR + lane] = fi;
      out[(size_t)NPIX * DIM + (size_t)NPIX * SPAR + (size_t)n * SPAR + lane] = fc;
    }
  }
}

// ---------------------------------------------------------------------------
// Fallback single-wave OMP (tiny-workspace path; R10 kernel). Unchanged.
// ---------------------------------------------------------------------------
__global__ __launch_bounds__(64) void k_omp_fb(const float* __restrict__ X,
                                               const float* __restrict__ D,
                                               const float* __restrict__ G,
                                               const float* __restrict__ Gd,
                                               float* __restrict__ out) {
  const int lane = threadIdx.x & 63;
  const int lane16 = lane * 16;
  const int n = __builtin_amdgcn_readfirstlane(blockIdx.x);

  float hb[16];
  {
    double a[16];
#pragma unroll
    for (int j = 0; j < 16; ++j) a[j] = 0.0;
    for (int d = 0; d < DIM; ++d) {
      float xd = X[(size_t)d * NPIX + n];
#pragma unroll
      for (int j = 0; j < 16; ++j)
        a[j] += (double)xd * (double)D[(size_t)d * NATOM + lane16 + j];
    }
#pragma unroll
    for (int j = 0; j < 16; ++j) hb[j] = (float)a[j];
  }
#pragma unroll
  for (int j = 0; j < 16; ++j) asm volatile("" : "+v"(hb[j]));

  int selI[SPAR];
  float rows[SPAR - 1][16];
  float Lm[SPAR][SPAR], invL[SPAR], ysel[SPAR], coefF[SPAR];

#pragma unroll 8
  for (int s = 0; s < SPAR; ++s) {
    float h[16];
#pragma unroll
    for (int j = 0; j < 16; ++j) {
      float hv = hb[j];
#pragma unroll
      for (int i = 0; i < SPAR - 1; ++i)
        if (i < s) hv = fmaf(-coefF[i], rows[i][j], hv);
      h[j] = hv;
    }
    float m0 = fmaxf(fmaxf(fmaxf(fabsf(h[0]), fabsf(h[1])), fabsf(h[2])), fabsf(h[3]));
    float m1 = fmaxf(fmaxf(fmaxf(fabsf(h[4]), fabsf(h[5])), fabsf(h[6])), fabsf(h[7]));
    float m2 = fmaxf(fmaxf(fmaxf(fabsf(h[8]), fabsf(h[9])), fabsf(h[10])), fabsf(h[11]));
    float m3 = fmaxf(fmaxf(fmaxf(fabsf(h[12]), fabsf(h[13])), fabsf(h[14])), fabsf(h[15]));
    const float M = wave_max_bcast(fmaxf(fmaxf(m0, m1), fmaxf(m2, m3)));
    unsigned cand = NATOM;
#pragma unroll
    for (int j = 15; j >= 0; --j)
      cand = (fabsf(h[j]) == M) ? (unsigned)(lane16 + j) : cand;
    unsigned long long bal = __ballot(cand != (unsigned)NATOM);
    const int fl = __ffsll(bal) - 1;
    const int bk = __builtin_amdgcn_readlane((int)cand, fl);
    selI[s] = bk;
    const int bl = bk >> 4, bj = bk & 15;

    float v = 0.f;
#pragma unroll
    for (int j = 0; j < 16; ++j)
      if (j == bj) v = hb[j];
    const float hbs =
        __int_as_float(__builtin_amdgcn_readlane(__float_as_int(v), bl));

#pragma unroll
    for (int j = 0; j < 16; ++j)
      if (j == bj && lane == bl) hb[j] = __builtin_nanf("");

    if (s < SPAR - 1) {
#pragma unroll
      for (int q = 0; q < 4; ++q) {
        float4 rv = *reinterpret_cast<const float4*>(
            &G[(size_t)bk * NATOM + lane16 + q * 4]);
        rows[s][q * 4 + 0] = rv.x; rows[s][q * 4 + 1] = rv.y;
        rows[s][q * 4 + 2] = rv.z; rows[s][q * 4 + 3] = rv.w;
      }
    }

    const float diag = Gd[bk];
    float w[SPAR];
    float sq = 0.f;
#pragma unroll
    for (int i = 0; i < SPAR; ++i)
      if (i < s) {
        float a = G[(size_t)selI[i] * NATOM + bk];
#pragma unroll
        for (int t = 0; t < SPAR; ++t)
          if (t < i) a = fmaf(-Lm[i][t], w[t], a);
        w[i] = a * invL[i];
        sq += w[i] * w[i];
        Lm[s][i] = w[i];
      }
    float cc = diag - sq;
    if (cc < 1e-6f) cc = 1e-6f;
    invL[s] = 1.0f / sqrtf(cc);
    {
      float a = hbs;
#pragma unroll
      for (int t = 0; t < SPAR; ++t)
        if (t < s) a = fmaf(-Lm[s][t], ysel[t], a);
      ysel[s] = a * invL[s];
    }
#pragma unroll
    for (int i = SPAR - 1; i >= 0; --i)
      if (i <= s) {
        float a = ysel[i];
#pragma unroll
        for (int t = 0; t < SPAR; ++t)
          if (t > i && t <= s) a = fmaf(-Lm[t][i], coefF[t], a);
        coefF[i] = a * invL[i];
      }
    if (s < SPAR - 1) {
#pragma unroll
      for (int j = 0; j < 16; ++j) asm volatile("" : "+v"(rows[s][j]));
    }
  }

  double r = 0.0;
#pragma unroll
  for (int i = 0; i < SPAR; ++i)
    r += (double)coefF[i] * (double)D[(size_t)lane * NATOM + selI[i]];
  out[(size_t)n * DIM + lane] = (float)r;

  float fi = 0.f, fc = 0.f;
#pragma unroll
  for (int i = 0; i < SPAR; ++i)
    if (lane == i) { fi = (float)selI[i]; fc = coefF[i]; }
  if (lane < SPAR) {
    out[(size_t)NPIX * DIM + (size_t)n * SPAR + lane] = fi;
    out[(size_t)NPIX * DIM + (size_t)NPIX * SPAR + (size_t)n * SPAR + lane] = fc;
  }
}

__global__ __launch_bounds__(256) void k_gram(const float* __restrict__ D,
                                              float* __restrict__ G,
                                              float* __restrict__ Gd) {
  int k1 = blockIdx.x;
  __shared__ float d1[DIM];
  if (threadIdx.x < DIM) d1[threadIdx.x] = D[(size_t)threadIdx.x * NATOM + k1];
  __syncthreads();
  for (int k2 = threadIdx.x; k2 < NATOM; k2 += 256) {
    double acc = 0.0;
#pragma unroll
    for (int d = 0; d < DIM; ++d)
      acc += (double)d1[d] * (double)D[(size_t)d * NATOM + k2];
    float g = (float)acc;
    if (k2 == k1) {
      g += 1e-4f;
      Gd[k1] = g;
    }
    G[(size_t)k1 * NATOM + k2] = g;
  }
}

extern "C" void kernel_launch(void* const* d_in, const int* in_sizes, int n_in,
                              void* d_out, int out_size, void* d_ws,
                              size_t ws_size, hipStream_t stream) {
  const float* X = (const float*)d_in[0];  // [64, 16384]
  const float* D = (const float*)d_in[1];  // [64, 1024]
  float* out = (float*)d_out;              // [recon | I | coeffs] as fp32
  float* G = (float*)d_ws;                 // 4 MB
  float* Dt = G + (size_t)NATOM * NATOM;   // 256 KB
  float* Gd = Dt + (size_t)NATOM * DIM;    // 4 KB
  float* HB = Gd + NATOM;                  // 64 MB
  const size_t needFull =
      ((size_t)NATOM * NATOM + (size_t)NATOM * DIM + NATOM +
       (size_t)NPIX * NATOM) * sizeof(float);

  if (ws_size >= needFull) {
    k_pre<<<dim3(1344), dim3(256), 0, stream>>>(X, D, G, Dt, Gd, HB);
    k_omp2<<<dim3(NPIX), dim3(128), 0, stream>>>(HB, Dt, G, Gd, out);
  } else {
    k_gram<<<dim3(NATOM), dim3(256), 0, stream>>>(D, G, Gd);
    k_omp_fb<<<dim3(NPIX), dim3(64), 0, stream>>>(X, D, G, Gd, out);
  }
}